// Round 2
// baseline (164.201 us; speedup 1.0000x reference)
//
#include <hip/hip_runtime.h>

#define NS 1048576
#define NFLOW 8
#define HD 64
#define GT 8192

#define EMIN -7.5f
#define ESPAN 15.0f
#define GDEL (ESPAN / (float)(GT - 1))
#define GINV ((float)(GT - 1) / ESPAN)

// ws layout:
//   [0..7]    double S accumulator
//   [16..63]  float pr[9]: bm0,bm1,bm2, Lc00,Lc10,Lc11,Lc20,Lc21,Lc22
//   [64 .. 64+GT*16)            float4 tabAB[GT]  (A1,B1,A2,B2) indexed by eps0 grid
//   [64+GT*16 .. 64+GT*16+GT*4) float  tabLD[GT]

__device__ __forceinline__ void cholesky9(const float* __restrict__ L_tril,
                                          float* d) {
    // L = tril(L_tril) + 1e-6*I ; cov = L L^T ; chol(cov) in fp64
    double l00 = (double)L_tril[0] + 1e-6;
    double l10 = (double)L_tril[3];
    double l11 = (double)L_tril[4] + 1e-6;
    double l20 = (double)L_tril[6];
    double l21 = (double)L_tril[7];
    double l22 = (double)L_tril[8] + 1e-6;
    double c00 = l00 * l00;
    double c10 = l10 * l00;
    double c11 = l10 * l10 + l11 * l11;
    double c20 = l20 * l00;
    double c21 = l20 * l10 + l21 * l11;
    double c22 = l20 * l20 + l21 * l21 + l22 * l22;
    double d00 = sqrt(c00);
    double d10 = c10 / d00;
    double d20 = c20 / d00;
    double d11 = sqrt(c11 - d10 * d10);
    double d21 = (c21 - d20 * d10) / d11;
    double d22 = sqrt(c22 - d20 * d20 - d21 * d21);
    d[0] = (float)d00; d[1] = (float)d10; d[2] = (float)d11;
    d[3] = (float)d20; d[4] = (float)d21; d[5] = (float)d22;
}

// ---------- kernel 1: build composed-affine table (MLP + compose fused) ----------
// grid: GT/32 blocks x 256 threads.  thread = (point pl = tid&31, flow t = tid>>5)
__global__ void __launch_bounds__(256) k_build(
    const float* __restrict__ L_tril, const float* __restrict__ bm,
    const float* __restrict__ W1, const float* __restrict__ b1,
    const float* __restrict__ W2, const float* __restrict__ b2,
    const float* __restrict__ W3, const float* __restrict__ b3,
    char* __restrict__ ws) {
    int tid = threadIdx.x;
    int t = tid >> 5;
    int pl = tid & 31;
    int p = blockIdx.x * 32 + pl;

    float d[6];
    cholesky9(L_tril, d);
    float bm0 = bm[0];

    float e0 = fmaf(GDEL, (float)p, EMIN);
    float z0 = fmaf(d[0], e0, bm0);

    const float* w1  = W1 + t * HD;       // (HD,1)
    const float* bb1 = b1 + t * HD;
    const float* w2  = W2 + t * HD * HD;  // (HD,HD)
    const float* bb2 = b2 + t * HD;
    const float* w3  = W3 + t * 4 * HD;   // (4,HD)
    const float* bb3 = b3 + t * 4;

    float h1[HD];
#pragma unroll
    for (int k = 0; k < HD; k++) {
        float v = fmaf(z0, w1[k], bb1[k]);
        h1[k] = v > 0.f ? v : 0.f;
    }
    float p0 = bb3[0], p1 = bb3[1], p2 = bb3[2], p3 = bb3[3];
    for (int j = 0; j < HD; j++) {
        const float* r = w2 + j * HD;
        float a0 = 0.f, a1 = 0.f, a2 = 0.f, a3 = 0.f;
#pragma unroll
        for (int k = 0; k < HD; k += 4) {
            a0 = fmaf(r[k],     h1[k],     a0);
            a1 = fmaf(r[k + 1], h1[k + 1], a1);
            a2 = fmaf(r[k + 2], h1[k + 2], a2);
            a3 = fmaf(r[k + 3], h1[k + 3], a3);
        }
        float acc = bb2[j] + ((a0 + a1) + (a2 + a3));
        float h = acc > 0.f ? acc : 0.f;
        p0 = fmaf(w3[j],          h, p0);
        p1 = fmaf(w3[HD + j],     h, p1);
        p2 = fmaf(w3[2 * HD + j], h, p2);
        p3 = fmaf(w3[3 * HD + j], h, p3);
    }

    __shared__ float4 part[NFLOW][32];
    part[t][pl] = make_float4(tanhf(p0), tanhf(p1), p2, p3);
    __syncthreads();

    if (tid < 32) {
        float A1 = 1.f, B1 = 0.f, A2 = 1.f, B2 = 0.f, LD = 0.f;
#pragma unroll
        for (int f = 0; f < NFLOW; f++) {
            float4 v = part[f][tid];
            float a1 = expf(v.x), a2 = expf(v.y);
            A1 *= a1; B1 = fmaf(B1, a1, v.z);
            A2 *= a2; B2 = fmaf(B2, a2, v.w);
            LD += v.x + v.y;
        }
        int gp = blockIdx.x * 32 + tid;
        ((float4*)(ws + 64))[gp] = make_float4(A1, B1, A2, B2);
        ((float*)(ws + 64 + GT * 16))[gp] = LD;
    }
    if (tid == 0 && blockIdx.x == 0) {
        *(double*)ws = 0.0;
        float* pr = (float*)(ws + 16);
        pr[0] = bm0; pr[1] = bm[1]; pr[2] = bm[2];
        pr[3] = d[0]; pr[4] = d[1]; pr[5] = d[2];
        pr[6] = d[3]; pr[7] = d[4]; pr[8] = d[5];
    }
}

// ---------- kernel 2: main per-sample pass ----------
__global__ void __launch_bounds__(256) k_main(const float4* __restrict__ eps4,
                                              char* __restrict__ ws,
                                              float* __restrict__ out) {
    int i = blockIdx.x * blockDim.x + threadIdx.x;
    const float* pr = (const float*)(ws + 16);
    float bm0 = pr[0], bm1 = pr[1], bm2 = pr[2];
    float Lc00 = pr[3], Lc10 = pr[4], Lc11 = pr[5], Lc20 = pr[6], Lc21 = pr[7], Lc22 = pr[8];
    const float4* tabAB = (const float4*)(ws + 64);
    const float* tabLD = (const float*)(ws + 64 + GT * 16);

    float4 a = eps4[3 * i], b = eps4[3 * i + 1], c = eps4[3 * i + 2];
    float e0[4] = {a.x, a.w, b.z, c.y};
    float e1[4] = {a.y, b.x, b.w, c.z};
    float e2[4] = {a.z, b.y, c.x, c.w};
    float zo[12], ld[4];
    float lsum = 0.f;
#pragma unroll
    for (int s = 0; s < 4; s++) {
        float z0 = fmaf(Lc00, e0[s], bm0);
        float z1 = fmaf(Lc11, e1[s], fmaf(Lc10, e0[s], bm1));
        float z2 = fmaf(Lc22, e2[s], fmaf(Lc21, e1[s], fmaf(Lc20, e0[s], bm2)));
        float u = (e0[s] - EMIN) * GINV;
        u = fminf(fmaxf(u, 0.f), (float)(GT - 1));
        int g = (int)u;
        if (g > GT - 2) g = GT - 2;
        float f = u - (float)g;
        float4 t0 = tabAB[g], t1 = tabAB[g + 1];
        float A1 = fmaf(f, t1.x - t0.x, t0.x);
        float B1 = fmaf(f, t1.y - t0.y, t0.y);
        float A2 = fmaf(f, t1.z - t0.z, t0.z);
        float B2 = fmaf(f, t1.w - t0.w, t0.w);
        float l0 = tabLD[g];
        float LD = fmaf(f, tabLD[g + 1] - l0, l0);
        float z1f = fmaf(z1, A1, B1);
        float z2f = fmaf(z2, A2, B2);
        zo[3 * s]     = z0;
        zo[3 * s + 1] = expf(z1f);
        zo[3 * s + 2] = expf(z2f);
        ld[s] = LD;
        lsum += z1f + z2f;
    }
    float4* o4 = (float4*)out;
    o4[3 * i]     = make_float4(zo[0], zo[1], zo[2], zo[3]);
    o4[3 * i + 1] = make_float4(zo[4], zo[5], zo[6], zo[7]);
    o4[3 * i + 2] = make_float4(zo[8], zo[9], zo[10], zo[11]);
    ((float4*)(out + 3 * (size_t)NS))[i] = make_float4(ld[0], ld[1], ld[2], ld[3]);

    for (int o = 32; o > 0; o >>= 1) lsum += __shfl_down(lsum, o);
    __shared__ float sred[4];
    int lane = threadIdx.x & 63, wid = threadIdx.x >> 6;
    if (lane == 0) sred[wid] = lsum;
    __syncthreads();
    if (threadIdx.x == 0) {
        double tot = (double)sred[0] + (double)sred[1] + (double)sred[2] + (double)sred[3];
        atomicAdd((double*)ws, tot);
    }
}

// ---------- kernel 3: broadcast-add S to log_det ----------
__global__ void __launch_bounds__(256) k_adds(float* __restrict__ out,
                                              const char* __restrict__ ws) {
    int i = blockIdx.x * blockDim.x + threadIdx.x;
    float S = (float)(*(const double*)ws);
    float4* p = (float4*)(out + 3 * (size_t)NS);
    float4 v = p[i];
    v.x += S; v.y += S; v.z += S; v.w += S;
    p[i] = v;
}

extern "C" void kernel_launch(void* const* d_in, const int* in_sizes, int n_in,
                              void* d_out, int out_size, void* d_ws, size_t ws_size,
                              hipStream_t stream) {
    const float* L_tril = (const float*)d_in[0];
    const float* bm     = (const float*)d_in[1];
    const float* W1     = (const float*)d_in[2];
    const float* b1     = (const float*)d_in[3];
    const float* W2     = (const float*)d_in[4];
    const float* b2     = (const float*)d_in[5];
    const float* W3     = (const float*)d_in[6];
    const float* b3     = (const float*)d_in[7];
    const float* eps    = (const float*)d_in[8];
    char* ws = (char*)d_ws;
    float* out = (float*)d_out;

    k_build<<<GT / 32, 256, 0, stream>>>(L_tril, bm, W1, b1, W2, b2, W3, b3, ws);
    k_main<<<NS / 4 / 256, 256, 0, stream>>>((const float4*)eps, ws, out);
    k_adds<<<NS / 4 / 256, 256, 0, stream>>>(out, ws);
}

// Round 3
// 118.019 us; speedup vs baseline: 1.3913x; 1.3913x over previous
//
#include <hip/hip_runtime.h>

#define NS 1048576
#define NFLOW 8
#define HD 64
#define GT 2048
#define PTS 8  // grid points per k_build block

#define EMIN -7.5f
#define ESPAN 15.0f
#define GDEL (ESPAN / (float)(GT - 1))
#define GINV ((float)(GT - 1) / ESPAN)

// ws layout:
//   [0..7]      double S accumulator
//   [16..52)    float pr[9]: bm0,bm1,bm2, Lc00,Lc10,Lc11,Lc20,Lc21,Lc22
//   [64, +GT*16)        float4 tabAB[GT]   (A1,B1,A2,B2), indexed by eps0 grid
//   [WS_LD, +GT*4)      float  tabLD[GT]
//   [WS_PART, +NFLOW*GT*16) float4 partial[NFLOW][GT]  (s0,s1,sh0,sh1)
#define WS_AB   64
#define WS_LD   (WS_AB + GT * 16)
#define WS_PART ((WS_LD + GT * 4 + 63) & ~63)

__device__ __forceinline__ void cholesky9(const float* __restrict__ L_tril, float* d) {
    double l00 = (double)L_tril[0] + 1e-6;
    double l10 = (double)L_tril[3];
    double l11 = (double)L_tril[4] + 1e-6;
    double l20 = (double)L_tril[6];
    double l21 = (double)L_tril[7];
    double l22 = (double)L_tril[8] + 1e-6;
    double c00 = l00 * l00;
    double c10 = l10 * l00;
    double c11 = l10 * l10 + l11 * l11;
    double c20 = l20 * l00;
    double c21 = l20 * l10 + l21 * l11;
    double c22 = l20 * l20 + l21 * l21 + l22 * l22;
    double d00 = sqrt(c00);
    double d10 = c10 / d00;
    double d20 = c20 / d00;
    double d11 = sqrt(c11 - d10 * d10);
    double d21 = (c21 - d20 * d10) / d11;
    double d22 = sqrt(c22 - d20 * d20 - d21 * d21);
    d[0] = (float)d00; d[1] = (float)d10; d[2] = (float)d11;
    d[3] = (float)d20; d[4] = (float)d21; d[5] = (float)d22;
}

// ---------- kernel 1: per-flow MLP table, thread = (point, hidden-neuron j) ----------
// grid: NFLOW * GT/PTS blocks x 512 threads. block = one flow x PTS points.
__global__ void __launch_bounds__(512) k_build(
    const float* __restrict__ L_tril, const float* __restrict__ bm,
    const float* __restrict__ W1, const float* __restrict__ b1,
    const float* __restrict__ W2, const float* __restrict__ b2,
    const float* __restrict__ W3, const float* __restrict__ b3,
    char* __restrict__ ws) {
    const int CHUNKS = GT / PTS;
    int t = blockIdx.x / CHUNKS;
    int chunk = blockIdx.x % CHUNKS;
    int tid = threadIdx.x;
    int pg = tid >> 6;   // point group 0..PTS-1
    int j = tid & 63;    // hidden neuron
    int p = chunk * PTS + pg;

    __shared__ float w2s[HD * 65];  // padded stride 65 -> bank (j+k)%32, 2-way free
    __shared__ float w1s[HD], b1s[HD], b2s[HD], w3s[4 * HD];
    __shared__ float h1s[PTS][HD];

    for (int idx = tid; idx < HD * HD; idx += 512)
        w2s[(idx >> 6) * 65 + (idx & 63)] = W2[t * HD * HD + idx];
    if (tid < HD) {
        w1s[tid] = W1[t * HD + tid];
        b1s[tid] = b1[t * HD + tid];
        b2s[tid] = b2[t * HD + tid];
    }
    if (tid < 4 * HD) w3s[tid] = W3[t * 4 * HD + tid];
    __syncthreads();

    // layer 1: lane j computes h1[j] for its point
    float Lc00 = fabsf(L_tril[0] + 1e-6f);  // diag of chol(L L^T) = |L00|
    float z0 = fmaf(Lc00, fmaf(GDEL, (float)p, EMIN), bm[0]);
    float h1 = fmaf(z0, w1s[j], b1s[j]);
    h1s[pg][j] = h1 > 0.f ? h1 : 0.f;
    __syncthreads();

    // layer 2: h2[j] = relu(dot(w2[j,:], h1) + b2[j])
    float a0 = 0.f, a1 = 0.f;
    const float* row = &w2s[j * 65];
    const float* hh = h1s[pg];
#pragma unroll
    for (int k = 0; k < HD; k += 2) {
        a0 = fmaf(row[k], hh[k], a0);
        a1 = fmaf(row[k + 1], hh[k + 1], a1);
    }
    float acc = b2s[j] + a0 + a1;
    float h2 = acc > 0.f ? acc : 0.f;

    // layer 3: 4 outputs, reduce over j with shuffles
    float c0 = w3s[j] * h2;
    float c1 = w3s[HD + j] * h2;
    float c2 = w3s[2 * HD + j] * h2;
    float c3 = w3s[3 * HD + j] * h2;
#pragma unroll
    for (int o = 32; o > 0; o >>= 1) {
        c0 += __shfl_xor(c0, o);
        c1 += __shfl_xor(c1, o);
        c2 += __shfl_xor(c2, o);
        c3 += __shfl_xor(c3, o);
    }
    if (j == 0) {
        const float* bb3 = b3 + t * 4;
        ((float4*)(ws + WS_PART))[t * GT + p] =
            make_float4(tanhf(c0 + bb3[0]), tanhf(c1 + bb3[1]), c2 + bb3[2], c3 + bb3[3]);
    }
}

// ---------- kernel 2: compose the 8 flows per grid point; also Cholesky + S init ----------
__global__ void __launch_bounds__(256) k_compose(const float* __restrict__ L_tril,
                                                 const float* __restrict__ bm,
                                                 char* __restrict__ ws) {
    int p = blockIdx.x * blockDim.x + threadIdx.x;
    const float4* partial = (const float4*)(ws + WS_PART);
    float A1 = 1.f, B1 = 0.f, A2 = 1.f, B2 = 0.f, LD = 0.f;
#pragma unroll
    for (int t = 0; t < NFLOW; t++) {
        float4 v = partial[t * GT + p];
        float a1 = expf(v.x), a2 = expf(v.y);
        A1 *= a1; B1 = fmaf(B1, a1, v.z);
        A2 *= a2; B2 = fmaf(B2, a2, v.w);
        LD += v.x + v.y;
    }
    ((float4*)(ws + WS_AB))[p] = make_float4(A1, B1, A2, B2);
    ((float*)(ws + WS_LD))[p] = LD;
    if (p == 0) {
        *(double*)ws = 0.0;
        float d[6];
        cholesky9(L_tril, d);
        float* pr = (float*)(ws + 16);
        pr[0] = bm[0]; pr[1] = bm[1]; pr[2] = bm[2];
        pr[3] = d[0]; pr[4] = d[1]; pr[5] = d[2];
        pr[6] = d[3]; pr[7] = d[4]; pr[8] = d[5];
    }
}

// ---------- kernel 3: main per-sample pass ----------
__global__ void __launch_bounds__(256) k_main(const float4* __restrict__ eps4,
                                              char* __restrict__ ws,
                                              float* __restrict__ out) {
    int i = blockIdx.x * blockDim.x + threadIdx.x;
    const float* pr = (const float*)(ws + 16);
    float bm0 = pr[0], bm1 = pr[1], bm2 = pr[2];
    float Lc00 = pr[3], Lc10 = pr[4], Lc11 = pr[5], Lc20 = pr[6], Lc21 = pr[7], Lc22 = pr[8];
    const float4* tabAB = (const float4*)(ws + WS_AB);
    const float* tabLD = (const float*)(ws + WS_LD);

    float4 a = eps4[3 * i], b = eps4[3 * i + 1], c = eps4[3 * i + 2];
    float e0[4] = {a.x, a.w, b.z, c.y};
    float e1[4] = {a.y, b.x, b.w, c.z};
    float e2[4] = {a.z, b.y, c.x, c.w};
    float zo[12], ld[4];
    float lsum = 0.f;
#pragma unroll
    for (int s = 0; s < 4; s++) {
        float z0 = fmaf(Lc00, e0[s], bm0);
        float z1 = fmaf(Lc11, e1[s], fmaf(Lc10, e0[s], bm1));
        float z2 = fmaf(Lc22, e2[s], fmaf(Lc21, e1[s], fmaf(Lc20, e0[s], bm2)));
        float u = (e0[s] - EMIN) * GINV;
        u = fminf(fmaxf(u, 0.f), (float)(GT - 1));
        int g = (int)u;
        if (g > GT - 2) g = GT - 2;
        float f = u - (float)g;
        float4 t0 = tabAB[g], t1 = tabAB[g + 1];
        float A1 = fmaf(f, t1.x - t0.x, t0.x);
        float B1 = fmaf(f, t1.y - t0.y, t0.y);
        float A2 = fmaf(f, t1.z - t0.z, t0.z);
        float B2 = fmaf(f, t1.w - t0.w, t0.w);
        float l0 = tabLD[g];
        float LD = fmaf(f, tabLD[g + 1] - l0, l0);
        float z1f = fmaf(z1, A1, B1);
        float z2f = fmaf(z2, A2, B2);
        zo[3 * s]     = z0;
        zo[3 * s + 1] = expf(z1f);
        zo[3 * s + 2] = expf(z2f);
        ld[s] = LD;
        lsum += z1f + z2f;
    }
    float4* o4 = (float4*)out;
    o4[3 * i]     = make_float4(zo[0], zo[1], zo[2], zo[3]);
    o4[3 * i + 1] = make_float4(zo[4], zo[5], zo[6], zo[7]);
    o4[3 * i + 2] = make_float4(zo[8], zo[9], zo[10], zo[11]);
    ((float4*)(out + 3 * (size_t)NS))[i] = make_float4(ld[0], ld[1], ld[2], ld[3]);

    for (int o = 32; o > 0; o >>= 1) lsum += __shfl_down(lsum, o);
    __shared__ float sred[4];
    int lane = threadIdx.x & 63, wid = threadIdx.x >> 6;
    if (lane == 0) sred[wid] = lsum;
    __syncthreads();
    if (threadIdx.x == 0) {
        double tot = (double)sred[0] + (double)sred[1] + (double)sred[2] + (double)sred[3];
        atomicAdd((double*)ws, tot);
    }
}

// ---------- kernel 4: broadcast-add S to log_det ----------
__global__ void __launch_bounds__(256) k_adds(float* __restrict__ out,
                                              const char* __restrict__ ws) {
    int i = blockIdx.x * blockDim.x + threadIdx.x;
    float S = (float)(*(const double*)ws);
    float4* p = (float4*)(out + 3 * (size_t)NS);
    float4 v = p[i];
    v.x += S; v.y += S; v.z += S; v.w += S;
    p[i] = v;
}

extern "C" void kernel_launch(void* const* d_in, const int* in_sizes, int n_in,
                              void* d_out, int out_size, void* d_ws, size_t ws_size,
                              hipStream_t stream) {
    const float* L_tril = (const float*)d_in[0];
    const float* bm     = (const float*)d_in[1];
    const float* W1     = (const float*)d_in[2];
    const float* b1     = (const float*)d_in[3];
    const float* W2     = (const float*)d_in[4];
    const float* b2     = (const float*)d_in[5];
    const float* W3     = (const float*)d_in[6];
    const float* b3     = (const float*)d_in[7];
    const float* eps    = (const float*)d_in[8];
    char* ws = (char*)d_ws;
    float* out = (float*)d_out;

    k_build<<<NFLOW * (GT / PTS), 512, 0, stream>>>(L_tril, bm, W1, b1, W2, b2, W3, b3, ws);
    k_compose<<<GT / 256, 256, 0, stream>>>(L_tril, bm, ws);
    k_main<<<NS / 4 / 256, 256, 0, stream>>>((const float4*)eps, ws, out);
    k_adds<<<NS / 4 / 256, 256, 0, stream>>>(out, ws);
}